// Round 2
// baseline (1324.241 us; speedup 1.0000x reference)
//
#include <hip/hip_runtime.h>

// Problem constants (from reference)
constexpr int NUM_SEQS  = 32;
constexpr int KV_LEN    = 2048;
constexpr int NUM_HEADS = 16;
constexpr int HEAD_SIZE = 128;
constexpr float SCALE   = 0.08838834764831845f;

constexpr int HSTRIDE = NUM_HEADS * HEAD_SIZE;                    // floats per slot (2048)
constexpr size_t KV_PLANE = (size_t)NUM_SEQS * KV_LEN * HSTRIDE;  // elements in K plane

// Split-KV decode: each block handles one (seq, head, partition) of PART
// positions, producing an unnormalized partial softmax-attention:
//   m  = max score in partition
//   l  = sum exp(score - m)
//   acc[d] = sum exp(score - m) * V[t][d]
// A second kernel combines the NPART partials per (seq, head).
constexpr int NPART = 8;
constexpr int PART  = KV_LEN / NPART;     // 256 positions per partition

// 256 threads = 8 half-waves of 32 lanes. Each half-wave handles 8 positions
// per iteration (8 independent float4 loads per lane in flight), 4 iterations
// covering the 256-position partition.
__global__ __launch_bounds__(256, 4)
void decode_partial(const float* __restrict__ q,
                    const float* __restrict__ knew,
                    const float* __restrict__ vnew,
                    const float* __restrict__ kv,
                    const int*  __restrict__ slot_map,
                    float* __restrict__ acc_ws,
                    float* __restrict__ ml_ws)
{
    const int bid  = blockIdx.x;            // s*(16*8) + h*8 + p
    const int p    = bid & (NPART - 1);
    const int h    = (bid >> 3) & (NUM_HEADS - 1);
    const int s    = bid >> 7;
    const int tid  = threadIdx.x;
    const int half = tid >> 5;              // 0..7
    const int lane = tid & 31;

    __shared__ float sc[PART];              // scores -> exp values (1 KB)
    __shared__ float red[4];
    __shared__ float part[8][HEAD_SIZE];    // per-half partial acc (4 KB)

    const int qoff = (s * NUM_HEADS + h) * HEAD_SIZE;
    const float* kbase = kv + (size_t)s * KV_LEN * HSTRIDE + (size_t)h * HEAD_SIZE;
    const float* vbase = kbase + KV_PLANE;
    const int t_new = slot_map[s] - s * KV_LEN;   // position replaced by new token
    const int tbase = p * PART;

    const float4 qv = *reinterpret_cast<const float4*>(q + qoff + lane * 4);

    // ---------------- Phase 1: scores ----------------
    #pragma unroll 1
    for (int it = 0; it < 4; ++it) {
        const int t0 = tbase + it * 64 + half * 8;

        const float* pp[8];
        #pragma unroll
        for (int j = 0; j < 8; ++j) {
            const int t = t0 + j;
            pp[j] = (t == t_new) ? (knew + qoff) : (kbase + (size_t)t * HSTRIDE);
        }
        float4 kk[8];
        #pragma unroll
        for (int j = 0; j < 8; ++j)         // 8 independent loads issued back-to-back
            kk[j] = *reinterpret_cast<const float4*>(pp[j] + lane * 4);

        float d[8];
        #pragma unroll
        for (int j = 0; j < 8; ++j)
            d[j] = fmaf(kk[j].x, qv.x, fmaf(kk[j].y, qv.y,
                   fmaf(kk[j].z, qv.z, kk[j].w * qv.w)));

        #pragma unroll
        for (int off = 16; off > 0; off >>= 1) {
            #pragma unroll
            for (int j = 0; j < 8; ++j) d[j] += __shfl_xor(d[j], off);
        }
        if (lane == 0) {
            const int o = it * 64 + half * 8;   // local index within partition
            #pragma unroll
            for (int j = 0; j < 8; ++j) sc[o + j] = d[j] * SCALE;
        }
    }
    __syncthreads();

    // ---------------- partition softmax (one score per thread) ----------------
    float m = sc[tid];
    #pragma unroll
    for (int off = 32; off > 0; off >>= 1) m = fmaxf(m, __shfl_xor(m, off));
    if ((tid & 63) == 0) red[tid >> 6] = m;
    __syncthreads();
    m = fmaxf(fmaxf(red[0], red[1]), fmaxf(red[2], red[3]));

    const float e = __expf(sc[tid] - m);
    float l = e;
    #pragma unroll
    for (int off = 32; off > 0; off >>= 1) l += __shfl_xor(l, off);
    __syncthreads();                 // protect red[] reuse
    sc[tid] = e;                     // publish exp values
    if ((tid & 63) == 0) red[tid >> 6] = l;
    __syncthreads();
    l = red[0] + red[1] + red[2] + red[3];

    // ---------------- Phase 2: acc = exp . V ----------------
    float4 acc = make_float4(0.f, 0.f, 0.f, 0.f);
    #pragma unroll 1
    for (int it = 0; it < 4; ++it) {
        const int t0 = tbase + it * 64 + half * 8;

        const float* pp[8];
        #pragma unroll
        for (int j = 0; j < 8; ++j) {
            const int t = t0 + j;
            pp[j] = (t == t_new) ? (vnew + qoff) : (vbase + (size_t)t * HSTRIDE);
        }
        float4 vv[8];
        #pragma unroll
        for (int j = 0; j < 8; ++j)
            vv[j] = *reinterpret_cast<const float4*>(pp[j] + lane * 4);

        const int o = it * 64 + half * 8;
        #pragma unroll
        for (int j = 0; j < 8; ++j) {
            const float w = sc[o + j];       // LDS broadcast
            acc.x = fmaf(w, vv[j].x, acc.x);
            acc.y = fmaf(w, vv[j].y, acc.y);
            acc.z = fmaf(w, vv[j].z, acc.z);
            acc.w = fmaf(w, vv[j].w, acc.w);
        }
    }

    *reinterpret_cast<float4*>(&part[half][lane * 4]) = acc;
    __syncthreads();

    if (tid < HEAD_SIZE) {
        float o = 0.f;
        #pragma unroll
        for (int i = 0; i < 8; ++i) o += part[i][tid];
        acc_ws[(size_t)bid * HEAD_SIZE + tid] = o;
    }
    if (tid == 0) {
        ml_ws[bid * 2 + 0] = m;
        ml_ws[bid * 2 + 1] = l;
    }
}

// Combine NPART partials per (seq, head): standard flash-decoding merge.
__global__ __launch_bounds__(128)
void decode_combine(const float* __restrict__ acc_ws,
                    const float* __restrict__ ml_ws,
                    float* __restrict__ out)
{
    const int sh = blockIdx.x;       // seq*16 + head
    const int d  = threadIdx.x;      // 0..127

    float M = -1e30f;
    #pragma unroll
    for (int p = 0; p < NPART; ++p)
        M = fmaxf(M, ml_ws[(sh * NPART + p) * 2]);

    float L = 0.f, o = 0.f;
    #pragma unroll
    for (int p = 0; p < NPART; ++p) {
        const float mp = ml_ws[(sh * NPART + p) * 2 + 0];
        const float lp = ml_ws[(sh * NPART + p) * 2 + 1];
        const float w  = __expf(mp - M);
        L += w * lp;
        o = fmaf(w, acc_ws[(size_t)(sh * NPART + p) * HEAD_SIZE + d], o);
    }
    out[sh * HEAD_SIZE + d] = o / L;
}

extern "C" void kernel_launch(void* const* d_in, const int* in_sizes, int n_in,
                              void* d_out, int out_size, void* d_ws, size_t ws_size,
                              hipStream_t stream) {
    const float* q    = (const float*)d_in[0];
    const float* k    = (const float*)d_in[1];
    const float* v    = (const float*)d_in[2];
    const float* kv   = (const float*)d_in[3];
    const int*   slot = (const int*)d_in[4];
    float* out = (float*)d_out;

    constexpr int NBLK = NUM_SEQS * NUM_HEADS * NPART;   // 4096
    float* acc_ws = (float*)d_ws;                        // NBLK * 128 floats
    float* ml_ws  = acc_ws + (size_t)NBLK * HEAD_SIZE;   // NBLK * 2 floats

    hipLaunchKernelGGL(decode_partial, dim3(NBLK), dim3(256), 0, stream,
                       q, k, v, kv, slot, acc_ws, ml_ws);
    hipLaunchKernelGGL(decode_combine, dim3(NUM_SEQS * NUM_HEADS), dim3(128), 0, stream,
                       acc_ws, ml_ws, out);
}